// Round 7
// baseline (175.803 us; speedup 1.0000x reference)
//
#include <hip/hip_runtime.h>
#include <math.h>
#include <float.h>

// Problem constants: B=4, S=2048, DIN=1024, DOUT=1024, E=16, K=2
#define DIN_  1024
#define DOUT_ 1024
#define NE    16
#define KK    2
#define NTOK  8192

// ws layout: [0,128KB)      : float wc[E][K][DIN]  compact expert columns
//            [128KB,192KB)  : float gwT[E][DIN]    transposed gate weights

// ---------------------------------------------------------------------------
// Prep kernel: build wc (expert columns 0,1) and gwT (gate_w transposed).
// ---------------------------------------------------------------------------
__global__ __launch_bounds__(256) void prep_kernel(
    const float* __restrict__ ew,   // [E, DIN, DOUT]
    const float* __restrict__ gw,   // [DIN, E]
    float* __restrict__ wc,         // [E, K, DIN]
    float* __restrict__ gwT)        // [E, DIN]
{
    int i = blockIdx.x * 256 + threadIdx.x;
    if (i < NE * KK * DIN_) {
        int d = i & (DIN_ - 1);
        int j = (i >> 10) & 1;
        int e = i >> 11;
        wc[i] = ew[(size_t)e * DIN_ * DOUT_ + (size_t)d * DOUT_ + j];
    } else if (i < NE * KK * DIN_ + NE * DIN_) {
        int k = i - NE * KK * DIN_;
        int d = k & (DIN_ - 1);
        int e = k >> 10;
        gwT[k] = gw[(size_t)d * NE + e];
    }
}

// ---------------------------------------------------------------------------
// Wave-autonomous fused kernel: one wave = 2 tokens, NO barriers, NO LDS.
// Gate weights read via gwT (coalesced, L1/L2-hot). x stays in registers
// across both gating and expert phases. Register budget ~110 (no spill).
// ---------------------------------------------------------------------------
__global__ __launch_bounds__(256, 4) void moe_wave_kernel(
    const float* __restrict__ x,        // [NTOK, DIN]
    const float* __restrict__ gwT,      // [E, DIN]
    const float* __restrict__ gate_b,   // [E]
    const float* __restrict__ ebias,    // [E]
    const float* __restrict__ wc,       // [E, K, DIN]
    const float* __restrict__ expert_b, // [E, DOUT]
    float* __restrict__ out_final,      // [NTOK, DOUT]
    float* __restrict__ out_probs,      // [NTOK, E]
    float* __restrict__ out_idx,        // [NTOK, K] as float
    int write_aux)
{
    const int lane = threadIdx.x & 63;
    const int wid  = threadIdx.x >> 6;                // 0..3
    const int tok0 = (blockIdx.x * 4 + wid) * 2;
    const int tok1 = tok0 + 1;

    // ---- x rows into registers, fully coalesced --------------------------
    const float4* x0p = (const float4*)(x + (size_t)tok0 * DIN_);
    const float4* x1p = (const float4*)(x + (size_t)tok1 * DIN_);
    float4 xr0[4], xr1[4];
#pragma unroll
    for (int c = 0; c < 4; c++) {
        xr0[c] = x0p[c * 64 + lane];
        xr1[c] = x1p[c * 64 + lane];
    }

    // ---- gating: coalesced gwT loads; 8 independent fp4-dots per expert --
    const float4* gwT4 = (const float4*)gwT;          // [E][256]
    float a0[NE], a1[NE];
#pragma unroll
    for (int e = 0; e < NE; e++) {
        float4 g0 = gwT4[e * 256 +   0 + lane];
        float4 g1 = gwT4[e * 256 +  64 + lane];
        float4 g2 = gwT4[e * 256 + 128 + lane];
        float4 g3 = gwT4[e * 256 + 192 + lane];
        a0[e] = xr0[0].x * g0.x + xr0[0].y * g0.y + xr0[0].z * g0.z + xr0[0].w * g0.w
              + xr0[1].x * g1.x + xr0[1].y * g1.y + xr0[1].z * g1.z + xr0[1].w * g1.w
              + xr0[2].x * g2.x + xr0[2].y * g2.y + xr0[2].z * g2.z + xr0[2].w * g2.w
              + xr0[3].x * g3.x + xr0[3].y * g3.y + xr0[3].z * g3.z + xr0[3].w * g3.w;
        a1[e] = xr1[0].x * g0.x + xr1[0].y * g0.y + xr1[0].z * g0.z + xr1[0].w * g0.w
              + xr1[1].x * g1.x + xr1[1].y * g1.y + xr1[1].z * g1.z + xr1[1].w * g1.w
              + xr1[2].x * g2.x + xr1[2].y * g2.y + xr1[2].z * g2.z + xr1[2].w * g2.w
              + xr1[3].x * g3.x + xr1[3].y * g3.y + xr1[3].z * g3.z + xr1[3].w * g3.w;
    }

    // ---- 64-lane butterfly: every lane gets full totals ------------------
#pragma unroll
    for (int e = 0; e < NE; e++) {
        float v0 = a0[e], v1 = a1[e];
#pragma unroll
        for (int m = 32; m >= 1; m >>= 1) {
            v0 += __shfl_xor(v0, m, 64);
            v1 += __shfl_xor(v1, m, 64);
        }
        float gb = gate_b[e];                         // SGPR (uniform)
        a0[e] = v0 + gb;                              // gate_output (pre-sigmoid)
        a1[e] = v1 + gb;
    }

    // ---- top-2 per token, redundantly on every lane (static indices) -----
    int i00 = 0, i01 = 0, i10 = 0, i11 = 0;
    float w00, w01, w10, w11;
    {
        float best = a0[0] + ebias[0], bgo = a0[0];
#pragma unroll
        for (int e = 1; e < NE; e++) {
            float lg = a0[e] + ebias[e];
            if (lg > best) { best = lg; bgo = a0[e]; i00 = e; }
        }
        float best2 = -FLT_MAX, bgo2 = 0.f;
#pragma unroll
        for (int e = 0; e < NE; e++) {
            float lg = a0[e] + ebias[e];
            bool c = (e != i00) && (lg > best2);
            if (c) { best2 = lg; bgo2 = a0[e]; i01 = e; }
        }
        float p0 = 1.f / (1.f + expf(-bgo));
        float p1 = 1.f / (1.f + expf(-bgo2));
        float inv = 1.f / (p0 + p1);
        w00 = p0 * inv; w01 = p1 * inv;
    }
    {
        float best = a1[0] + ebias[0], bgo = a1[0];
#pragma unroll
        for (int e = 1; e < NE; e++) {
            float lg = a1[e] + ebias[e];
            if (lg > best) { best = lg; bgo = a1[e]; i10 = e; }
        }
        float best2 = -FLT_MAX, bgo2 = 0.f;
#pragma unroll
        for (int e = 0; e < NE; e++) {
            float lg = a1[e] + ebias[e];
            bool c = (e != i10) && (lg > best2);
            if (c) { best2 = lg; bgo2 = a1[e]; i11 = e; }
        }
        float p0 = 1.f / (1.f + expf(-bgo));
        float p1 = 1.f / (1.f + expf(-bgo2));
        float inv = 1.f / (p0 + p1);
        w10 = p0 * inv; w11 = p1 * inv;
    }

    // ---- aux outputs (probs lanes 0..31 coalesced; idx lanes 0/1) --------
    if (write_aux) {
        int esel = lane & 15;
        float sg0 = 0.f, sg1 = 0.f;
#pragma unroll
        for (int e = 0; e < NE; e++) {
            bool m = (esel == e);
            sg0 = m ? a0[e] : sg0;
            sg1 = m ? a1[e] : sg1;
        }
        if (lane < 32) {
            int   t  = (lane < 16) ? tok0 : tok1;
            float sg = (lane < 16) ? sg0 : sg1;
            out_probs[(size_t)t * NE + esel] = 1.f / (1.f + expf(-sg));
        }
        if (lane == 0) {
            out_idx[(size_t)tok0 * KK + 0] = (float)i00;
            out_idx[(size_t)tok0 * KK + 1] = (float)i01;
        }
        if (lane == 1) {
            out_idx[(size_t)tok1 * KK + 0] = (float)i10;
            out_idx[(size_t)tok1 * KK + 1] = (float)i11;
        }
    }

    // ---- expert dots: reuse x registers, wc coalesced (L2-hot) -----------
    const float4* w0a = (const float4*)(wc + ((size_t)i00 * KK + 0) * DIN_);
    const float4* w0b = (const float4*)(wc + ((size_t)i01 * KK + 1) * DIN_);
    const float4* w1a = (const float4*)(wc + ((size_t)i10 * KK + 0) * DIN_);
    const float4* w1b = (const float4*)(wc + ((size_t)i11 * KK + 1) * DIN_);
    float d00 = 0.f, d01 = 0.f, d10 = 0.f, d11 = 0.f;
#pragma unroll
    for (int c = 0; c < 4; c++) {
        float4 p = w0a[c * 64 + lane];
        float4 q = w0b[c * 64 + lane];
        float4 u = w1a[c * 64 + lane];
        float4 v = w1b[c * 64 + lane];
        d00 += xr0[c].x * p.x + xr0[c].y * p.y + xr0[c].z * p.z + xr0[c].w * p.w;
        d01 += xr0[c].x * q.x + xr0[c].y * q.y + xr0[c].z * q.z + xr0[c].w * q.w;
        d10 += xr1[c].x * u.x + xr1[c].y * u.y + xr1[c].z * u.z + xr1[c].w * u.w;
        d11 += xr1[c].x * v.x + xr1[c].y * v.y + xr1[c].z * v.z + xr1[c].w * v.w;
    }
#pragma unroll
    for (int m = 32; m >= 1; m >>= 1) {
        d00 += __shfl_xor(d00, m, 64);
        d01 += __shfl_xor(d01, m, 64);
        d10 += __shfl_xor(d10, m, 64);
        d11 += __shfl_xor(d11, m, 64);
    }
    float f0 = w00 * (d00 + expert_b[(size_t)i00 * DOUT_ + 0])
             + w01 * (d01 + expert_b[(size_t)i01 * DOUT_ + 1]);
    float f1 = w10 * (d10 + expert_b[(size_t)i10 * DOUT_ + 0])
             + w11 * (d11 + expert_b[(size_t)i11 * DOUT_ + 1]);

    // ---- broadcast stores, fully coalesced -------------------------------
    float4 f0v = make_float4(f0, f0, f0, f0);
    float4 f1v = make_float4(f1, f1, f1, f1);
    float4* o0 = (float4*)(out_final + (size_t)tok0 * DOUT_);
    float4* o1 = (float4*)(out_final + (size_t)tok1 * DOUT_);
#pragma unroll
    for (int c = 0; c < 4; c++) {
        o0[c * 64 + lane] = f0v;
        o1[c * 64 + lane] = f1v;
    }
}

// ---------------------------------------------------------------------------
extern "C" void kernel_launch(void* const* d_in, const int* in_sizes, int n_in,
                              void* d_out, int out_size, void* d_ws, size_t ws_size,
                              hipStream_t stream) {
    const float* x        = (const float*)d_in[0];
    const float* gate_w   = (const float*)d_in[1];
    const float* gate_b   = (const float*)d_in[2];
    const float* expert_w = (const float*)d_in[3];
    const float* expert_b = (const float*)d_in[4];
    const float* ebias    = (const float*)d_in[5];
    float* out = (float*)d_out;

    float* wc  = (float*)d_ws;                          // 128 KB
    float* gwT = (float*)d_ws + (size_t)NE * KK * DIN_; // 64 KB

    float* out_final = out;
    float* out_probs = out + (size_t)NTOK * DOUT_;
    float* out_idx   = out_probs + (size_t)NTOK * NE;
    int write_aux = (out_size >= NTOK * DOUT_ + NTOK * NE + NTOK * KK) ? 1 : 0;

    int prep_n = NE * KK * DIN_ + NE * DIN_;            // 49152
    prep_kernel<<<(prep_n + 255) / 256, 256, 0, stream>>>(expert_w, gate_w, wc, gwT);
    // 8 tokens per block (2 per wave) -> 1024 blocks
    moe_wave_kernel<<<NTOK / 8, 256, 0, stream>>>(
        x, gwT, gate_b, ebias, wc, expert_b,
        out_final, out_probs, out_idx, write_aux);
}